// Round 7
// baseline (72.648 us; speedup 1.0000x reference)
//
#include <hip/hip_runtime.h>

// out[b,n] = softmax-gated mix of 4 activations of s[b,n], gates from a
// per-neuron 4->4->4 MLP (W1,b1,W2,b2). All f32.
// Thread owns neuron n. Block covers 16 batch rows; ALL 16 row inputs are
// preloaded into registers up front (16 independent loads -> MLP=16/wave,
// latency paid once and hidden under compute), then 4 iters x two
// independent v2f chains (ILP=2). Pure-C ext-vector ops (compiler forms
// v_pk_*_f32). Sigmoids via Pade(7,6) rational of tanh(z/2) (1 shared rcp
// for 4 hidden units); softmax in log2 domain shifted by l3 (3 exps/elem).

typedef float v2f __attribute__((ext_vector_type(2)));
#define SPL(x) ((v2f)(x))

static __device__ __forceinline__ v2f fma2(v2f a, v2f b, v2f c) {
    return __builtin_elementwise_fma(a, b, c);
}
static __device__ __forceinline__ v2f exp2v(v2f y) {
    v2f r; r.x = __builtin_amdgcn_exp2f(y.x); r.y = __builtin_amdgcn_exp2f(y.y); return r;
}
static __device__ __forceinline__ v2f rcpv(v2f d) {
    v2f r; r.x = __builtin_amdgcn_rcpf(d.x); r.y = __builtin_amdgcn_rcpf(d.y); return r;
}

__global__ __launch_bounds__(256, 4) void gatemix_kernel(
    const float* __restrict__ s,
    const float* __restrict__ W1,
    const float* __restrict__ b1,
    const float* __restrict__ W2,
    const float* __restrict__ b2,
    float* __restrict__ out,
    int B, int N)
{
    const int n = blockIdx.x * 256 + threadIdx.x;
    const float L2E = 1.44269504088896340736f;

    // Per-neuron params as splat pairs. W2/b2 pre-scaled by log2(e) so the
    // logits land in log2 domain for the softmax exp2s.
    const float4* W1v = (const float4*)W1;
    const float4* W2v = (const float4*)W2;
    v2f w1[4][4], w2[4][4], bb1[4], bb2[4];
    #pragma unroll
    for (int k = 0; k < 4; ++k) {
        float4 rw = W1v[(size_t)n*4 + k];                    // W1[n,k,:]
        w1[k][0] = SPL(rw.x); w1[k][1] = SPL(rw.y);
        w1[k][2] = SPL(rw.z); w1[k][3] = SPL(rw.w);
    }
    #pragma unroll
    for (int j = 0; j < 4; ++j) {
        float4 rw = W2v[(size_t)n*4 + j];                    // W2[n,j,:]
        w2[j][0] = SPL(rw.x*L2E); w2[j][1] = SPL(rw.y*L2E);
        w2[j][2] = SPL(rw.z*L2E); w2[j][3] = SPL(rw.w*L2E);
    }
    {
        float4 rb = ((const float4*)b1)[n];
        bb1[0]=SPL(rb.x); bb1[1]=SPL(rb.y); bb1[2]=SPL(rb.z); bb1[3]=SPL(rb.w);
        float4 rc = ((const float4*)b2)[n];
        bb2[0]=SPL(rc.x*L2E); bb2[1]=SPL(rc.y*L2E); bb2[2]=SPL(rc.z*L2E); bb2[3]=SPL(rc.w*L2E);
    }

    // sigmoid(z) = 0.5 + z*Np(z*z)*rcp(Dp(z*z)), Pade(7,6) of tanh(z/2).
    const v2f cn1 = SPL(8.0128205e-3f), cn2 = SPL(4.3706294e-5f), cn3 = SPL(2.8906051e-8f);
    const v2f cd1 = SPL(1.1538462e-1f), cd2 = SPL(1.4568765e-3f), cd3 = SPL(3.2372594e-6f);
    const v2f vQ = SPL(0.25f), vH = SPL(0.5f), vOne = SPL(1.0f);

    const int BCHUNK = 16;
    const size_t sN = (size_t)N;
    const float* sp = s   + (size_t)(blockIdx.y * BCHUNK) * sN + n;
    float*       op = out + (size_t)(blockIdx.y * BCHUNK) * sN + n;

    // Preload all 16 rows (8 v2f) -> 16 independent outstanding loads.
    v2f xr[8];
    #pragma unroll
    for (int r = 0; r < 8; ++r) {
        xr[r].x = sp[(size_t)(2*r)   * sN];
        xr[r].y = sp[(size_t)(2*r+1) * sN];
    }

    #pragma unroll
    for (int it = 0; it < 4; ++it) {
        v2f x[2], a0[2], a1[2], a2[2];
        x[0] = xr[2*it];
        x[1] = xr[2*it+1];

        #pragma unroll
        for (int c = 0; c < 2; ++c) {
            a0[c] = __builtin_elementwise_max(x[c], SPL(0.0f));
            a2[c] = __builtin_elementwise_min(x[c], SPL(0.0f));
            v2f u  = x[c] * x[c];
            v2f pn = fma2(fma2(fma2(cn3, u, cn2), u, cn1), u, vQ);
            v2f pd = fma2(fma2(fma2(cd3, u, cd2), u, cd1), u, vOne);
            a1[c]  = fma2(x[c] * pn, rcpv(pd), vH);
        }

        v2f h[2][4];
        #pragma unroll
        for (int c = 0; c < 2; ++c) {
            v2f qd[4], nm[4];
            #pragma unroll
            for (int j = 0; j < 4; ++j) {
                v2f zj = fma2(a0[c], w1[0][j],
                         fma2(a1[c], w1[1][j],
                         fma2(a2[c], w1[2][j],
                         fma2(x[c],  w1[3][j], bb1[j]))));
                v2f vv = zj * zj;
                v2f nn = fma2(fma2(fma2(cn3, vv, cn2), vv, cn1), vv, vQ);
                qd[j]  = fma2(fma2(fma2(cd3, vv, cd2), vv, cd1), vv, vOne);
                nm[j]  = zj * nn;
            }
            // one rcp for all 4 hidden sigmoids
            v2f p01 = qd[0] * qd[1];
            v2f p23 = qd[2] * qd[3];
            v2f rr  = rcpv(p01 * p23);
            v2f i01 = p23 * rr;              // 1/(qd0*qd1)
            v2f i23 = p01 * rr;              // 1/(qd2*qd3)
            h[c][0] = fma2(nm[0] * qd[1], i01, vH);
            h[c][1] = fma2(nm[1] * qd[0], i01, vH);
            h[c][2] = fma2(nm[2] * qd[3], i23, vH);
            h[c][3] = fma2(nm[3] * qd[2], i23, vH);
        }

        v2f o[2];
        #pragma unroll
        for (int c = 0; c < 2; ++c) {
            v2f l0 = fma2(h[c][0],w2[0][0], fma2(h[c][1],w2[1][0], fma2(h[c][2],w2[2][0], fma2(h[c][3],w2[3][0], bb2[0]))));
            v2f l1 = fma2(h[c][0],w2[0][1], fma2(h[c][1],w2[1][1], fma2(h[c][2],w2[2][1], fma2(h[c][3],w2[3][1], bb2[1]))));
            v2f l2 = fma2(h[c][0],w2[0][2], fma2(h[c][1],w2[1][2], fma2(h[c][2],w2[2][2], fma2(h[c][3],w2[3][2], bb2[2]))));
            v2f l3 = fma2(h[c][0],w2[0][3], fma2(h[c][1],w2[1][3], fma2(h[c][2],w2[2][3], fma2(h[c][3],w2[3][3], bb2[3]))));
            // softmax shifted by l3 (e3 == 1), log2 domain
            v2f e0 = exp2v(l0 - l3);
            v2f e1 = exp2v(l1 - l3);
            v2f e2 = exp2v(l2 - l3);
            v2f den = (e0 + e1) + (e2 + vOne);
            v2f num = fma2(e0, a0[c], fma2(e1, a1[c], fma2(e2, a2[c], x[c])));
            o[c] = num * rcpv(den);
        }

        op[(size_t)(4*it)   * sN] = o[0].x;
        op[(size_t)(4*it+1) * sN] = o[0].y;
        op[(size_t)(4*it+2) * sN] = o[1].x;
        op[(size_t)(4*it+3) * sN] = o[1].y;
    }
}

extern "C" void kernel_launch(void* const* d_in, const int* in_sizes, int n_in,
                              void* d_out, int out_size, void* d_ws, size_t ws_size,
                              hipStream_t stream) {
    const float* s  = (const float*)d_in[0];
    const float* W1 = (const float*)d_in[1];
    const float* b1 = (const float*)d_in[2];
    const float* W2 = (const float*)d_in[3];
    const float* b2 = (const float*)d_in[4];
    float* out = (float*)d_out;

    const int K = 4;
    const int N = in_sizes[2] / K;       // b1 is N*K
    const int B = in_sizes[0] / N;       // s is B*N

    dim3 grid(N / 256, B / 16);
    gatemix_kernel<<<grid, 256, 0, stream>>>(s, W1, b1, W2, b2, out, B, N);
}

// Round 8
// 44.886 us; speedup vs baseline: 1.6185x; 1.6185x over previous
//
#include <hip/hip_runtime.h>

// out[b,n] = softmax-gated mix of 4 activations of s[b,n], gates from a
// per-neuron 4->4->4 MLP (W1,b1,W2,b2). All f32.
// Thread owns neuron n. 4 rows/iter as two independent v2f chains (ILP=2),
// with software-prefetch depth 1: two zero-copy row buffers, unroll-by-2
// rolled loop (no full-unroll -> no R7-style register blowup/spill).
// Pure-C ext-vector ops (compiler forms v_pk_*_f32). Sigmoids via Pade(7,6)
// rational of tanh(z/2) (1 shared rcp per 4 hidden units); softmax in log2
// domain shifted by l3 (3 exps/elem).

typedef float v2f __attribute__((ext_vector_type(2)));
#define SPL(x) ((v2f)(x))

static __device__ __forceinline__ v2f fma2(v2f a, v2f b, v2f c) {
    return __builtin_elementwise_fma(a, b, c);
}
static __device__ __forceinline__ v2f exp2v(v2f y) {
    v2f r; r.x = __builtin_amdgcn_exp2f(y.x); r.y = __builtin_amdgcn_exp2f(y.y); return r;
}
static __device__ __forceinline__ v2f rcpv(v2f d) {
    v2f r; r.x = __builtin_amdgcn_rcpf(d.x); r.y = __builtin_amdgcn_rcpf(d.y); return r;
}

__global__ __launch_bounds__(256) void gatemix_kernel(
    const float* __restrict__ s,
    const float* __restrict__ W1,
    const float* __restrict__ b1,
    const float* __restrict__ W2,
    const float* __restrict__ b2,
    float* __restrict__ out,
    int B, int N)
{
    const int n = blockIdx.x * 256 + threadIdx.x;
    const float L2E = 1.44269504088896340736f;

    // Per-neuron params as splat pairs. W2/b2 pre-scaled by log2(e) so the
    // logits land in log2 domain for the softmax exp2s.
    const float4* W1v = (const float4*)W1;
    const float4* W2v = (const float4*)W2;
    v2f w1[4][4], w2[4][4], bb1[4], bb2[4];
    #pragma unroll
    for (int k = 0; k < 4; ++k) {
        float4 rw = W1v[(size_t)n*4 + k];                    // W1[n,k,:]
        w1[k][0] = SPL(rw.x); w1[k][1] = SPL(rw.y);
        w1[k][2] = SPL(rw.z); w1[k][3] = SPL(rw.w);
    }
    #pragma unroll
    for (int j = 0; j < 4; ++j) {
        float4 rw = W2v[(size_t)n*4 + j];                    // W2[n,j,:]
        w2[j][0] = SPL(rw.x*L2E); w2[j][1] = SPL(rw.y*L2E);
        w2[j][2] = SPL(rw.z*L2E); w2[j][3] = SPL(rw.w*L2E);
    }
    {
        float4 rb = ((const float4*)b1)[n];
        bb1[0]=SPL(rb.x); bb1[1]=SPL(rb.y); bb1[2]=SPL(rb.z); bb1[3]=SPL(rb.w);
        float4 rc = ((const float4*)b2)[n];
        bb2[0]=SPL(rc.x*L2E); bb2[1]=SPL(rc.y*L2E); bb2[2]=SPL(rc.z*L2E); bb2[3]=SPL(rc.w*L2E);
    }

    // sigmoid(z) = 0.5 + z*Np(z*z)*rcp(Dp(z*z)), Pade(7,6) of tanh(z/2).
    const v2f cn1 = SPL(8.0128205e-3f), cn2 = SPL(4.3706294e-5f), cn3 = SPL(2.8906051e-8f);
    const v2f cd1 = SPL(1.1538462e-1f), cd2 = SPL(1.4568765e-3f), cd3 = SPL(3.2372594e-6f);
    const v2f vQ = SPL(0.25f), vH = SPL(0.5f), vOne = SPL(1.0f);

    const int BCHUNK = 32;                    // rows per block, 8 iters x 4 rows
    const size_t sN = (size_t)N;
    const float* sp = s   + (size_t)(blockIdx.y * BCHUNK) * sN + n;
    float*       op = out + (size_t)(blockIdx.y * BCHUNK) * sN + n;

    // load 4 rows starting at r into two v2f
    auto load4 = [&](int r, v2f& xa, v2f& xb) {
        xa.x = sp[(size_t)(r)   * sN];
        xa.y = sp[(size_t)(r+1) * sN];
        xb.x = sp[(size_t)(r+2) * sN];
        xb.y = sp[(size_t)(r+3) * sN];
    };

    // full gate+store for 4 rows starting at r
    auto compute4 = [&](int r, v2f xA, v2f xB) {
        v2f x[2] = {xA, xB};
        v2f a0[2], a1[2], a2[2];
        #pragma unroll
        for (int c = 0; c < 2; ++c) {
            a0[c] = __builtin_elementwise_max(x[c], SPL(0.0f));
            a2[c] = __builtin_elementwise_min(x[c], SPL(0.0f));
            v2f u  = x[c] * x[c];
            v2f pn = fma2(fma2(fma2(cn3, u, cn2), u, cn1), u, vQ);
            v2f pd = fma2(fma2(fma2(cd3, u, cd2), u, cd1), u, vOne);
            a1[c]  = fma2(x[c] * pn, rcpv(pd), vH);
        }

        v2f h[2][4];
        #pragma unroll
        for (int c = 0; c < 2; ++c) {
            v2f qd[4], nm[4];
            #pragma unroll
            for (int j = 0; j < 4; ++j) {
                v2f zj = fma2(a0[c], w1[0][j],
                         fma2(a1[c], w1[1][j],
                         fma2(a2[c], w1[2][j],
                         fma2(x[c],  w1[3][j], bb1[j]))));
                v2f vv = zj * zj;
                v2f nn = fma2(fma2(fma2(cn3, vv, cn2), vv, cn1), vv, vQ);
                qd[j]  = fma2(fma2(fma2(cd3, vv, cd2), vv, cd1), vv, vOne);
                nm[j]  = zj * nn;
            }
            v2f p01 = qd[0] * qd[1];
            v2f p23 = qd[2] * qd[3];
            v2f rr  = rcpv(p01 * p23);
            v2f i01 = p23 * rr;              // 1/(qd0*qd1)
            v2f i23 = p01 * rr;              // 1/(qd2*qd3)
            h[c][0] = fma2(nm[0] * qd[1], i01, vH);
            h[c][1] = fma2(nm[1] * qd[0], i01, vH);
            h[c][2] = fma2(nm[2] * qd[3], i23, vH);
            h[c][3] = fma2(nm[3] * qd[2], i23, vH);
        }

        #pragma unroll
        for (int c = 0; c < 2; ++c) {
            v2f l0 = fma2(h[c][0],w2[0][0], fma2(h[c][1],w2[1][0], fma2(h[c][2],w2[2][0], fma2(h[c][3],w2[3][0], bb2[0]))));
            v2f l1 = fma2(h[c][0],w2[0][1], fma2(h[c][1],w2[1][1], fma2(h[c][2],w2[2][1], fma2(h[c][3],w2[3][1], bb2[1]))));
            v2f l2 = fma2(h[c][0],w2[0][2], fma2(h[c][1],w2[1][2], fma2(h[c][2],w2[2][2], fma2(h[c][3],w2[3][2], bb2[2]))));
            v2f l3 = fma2(h[c][0],w2[0][3], fma2(h[c][1],w2[1][3], fma2(h[c][2],w2[2][3], fma2(h[c][3],w2[3][3], bb2[3]))));
            v2f e0 = exp2v(l0 - l3);
            v2f e1 = exp2v(l1 - l3);
            v2f e2 = exp2v(l2 - l3);
            v2f den = (e0 + e1) + (e2 + vOne);
            v2f num = fma2(e0, a0[c], fma2(e1, a1[c], fma2(e2, a2[c], x[c])));
            v2f o = num * rcpv(den);
            op[(size_t)(r + 2*c)     * sN] = o.x;
            op[(size_t)(r + 2*c + 1) * sN] = o.y;
        }
    };

    // Software pipeline, depth 1, two zero-copy buffers, rolled loop.
    v2f xA, xB, yA, yB;
    load4(0, xA, xB);
    #pragma unroll 1
    for (int it = 0; it < 8; it += 2) {
        load4((it+1)*4, yA, yB);          // prefetch next iter (always valid)
        compute4(it*4, xA, xB);
        if (it + 2 < 8)
            load4((it+2)*4, xA, xB);      // prefetch into freed regs
        compute4((it+1)*4, yA, yB);
    }
}

extern "C" void kernel_launch(void* const* d_in, const int* in_sizes, int n_in,
                              void* d_out, int out_size, void* d_ws, size_t ws_size,
                              hipStream_t stream) {
    const float* s  = (const float*)d_in[0];
    const float* W1 = (const float*)d_in[1];
    const float* b1 = (const float*)d_in[2];
    const float* W2 = (const float*)d_in[3];
    const float* b2 = (const float*)d_in[4];
    float* out = (float*)d_out;

    const int K = 4;
    const int N = in_sizes[2] / K;       // b1 is N*K
    const int B = in_sizes[0] / N;       // s is B*N

    dim3 grid(N / 256, B / 32);
    gatemix_kernel<<<grid, 256, 0, stream>>>(s, W1, b1, W2, b2, out, B, N);
}

// Round 9
// 44.214 us; speedup vs baseline: 1.6431x; 1.0152x over previous
//
#include <hip/hip_runtime.h>

// out[b,n] = softmax-gated mix of 4 activations of s[b,n], gates from a
// per-neuron 4->4->4 MLP (W1,b1,W2,b2). All f32.
// Thread owns neuron n. Block covers 16 batch rows, ALL preloaded into
// registers up front (16 outstanding loads; compute iter k's first use waits
// only on its own 4 loads -> effective prefetch depth 3). NO occupancy cap
// (R7's launch_bounds(256,4) forced <=64 VGPR -> 150MB scratch spill; this
// run must show WRITE_SIZE == 64MB to be valid). 4 rows/iter as two
// independent v2f chains; pure-C ext-vector ops (compiler forms v_pk_*_f32).
// Sigmoids via Pade(7,6) rational of tanh(z/2) (1 shared rcp per 4 hidden
// units); softmax in log2 domain shifted by l3 (3 exps/elem).

typedef float v2f __attribute__((ext_vector_type(2)));
#define SPL(x) ((v2f)(x))

static __device__ __forceinline__ v2f fma2(v2f a, v2f b, v2f c) {
    return __builtin_elementwise_fma(a, b, c);
}
static __device__ __forceinline__ v2f exp2v(v2f y) {
    v2f r; r.x = __builtin_amdgcn_exp2f(y.x); r.y = __builtin_amdgcn_exp2f(y.y); return r;
}
static __device__ __forceinline__ v2f rcpv(v2f d) {
    v2f r; r.x = __builtin_amdgcn_rcpf(d.x); r.y = __builtin_amdgcn_rcpf(d.y); return r;
}

__global__ __launch_bounds__(256) void gatemix_kernel(
    const float* __restrict__ s,
    const float* __restrict__ W1,
    const float* __restrict__ b1,
    const float* __restrict__ W2,
    const float* __restrict__ b2,
    float* __restrict__ out,
    int B, int N)
{
    const int n = blockIdx.x * 256 + threadIdx.x;
    const float L2E = 1.44269504088896340736f;

    // Per-neuron params as splat pairs. W2/b2 pre-scaled by log2(e) so the
    // logits land in log2 domain for the softmax exp2s.
    const float4* W1v = (const float4*)W1;
    const float4* W2v = (const float4*)W2;
    v2f w1[4][4], w2[4][4], bb1[4], bb2[4];
    #pragma unroll
    for (int k = 0; k < 4; ++k) {
        float4 rw = W1v[(size_t)n*4 + k];                    // W1[n,k,:]
        w1[k][0] = SPL(rw.x); w1[k][1] = SPL(rw.y);
        w1[k][2] = SPL(rw.z); w1[k][3] = SPL(rw.w);
    }
    #pragma unroll
    for (int j = 0; j < 4; ++j) {
        float4 rw = W2v[(size_t)n*4 + j];                    // W2[n,j,:]
        w2[j][0] = SPL(rw.x*L2E); w2[j][1] = SPL(rw.y*L2E);
        w2[j][2] = SPL(rw.z*L2E); w2[j][3] = SPL(rw.w*L2E);
    }
    {
        float4 rb = ((const float4*)b1)[n];
        bb1[0]=SPL(rb.x); bb1[1]=SPL(rb.y); bb1[2]=SPL(rb.z); bb1[3]=SPL(rb.w);
        float4 rc = ((const float4*)b2)[n];
        bb2[0]=SPL(rc.x*L2E); bb2[1]=SPL(rc.y*L2E); bb2[2]=SPL(rc.z*L2E); bb2[3]=SPL(rc.w*L2E);
    }

    // sigmoid(z) = 0.5 + z*Np(z*z)*rcp(Dp(z*z)), Pade(7,6) of tanh(z/2).
    const v2f cn1 = SPL(8.0128205e-3f), cn2 = SPL(4.3706294e-5f), cn3 = SPL(2.8906051e-8f);
    const v2f cd1 = SPL(1.1538462e-1f), cd2 = SPL(1.4568765e-3f), cd3 = SPL(3.2372594e-6f);
    const v2f vQ = SPL(0.25f), vH = SPL(0.5f), vOne = SPL(1.0f);

    const int BCHUNK = 16;
    const size_t sN = (size_t)N;
    const float* sp = s   + (size_t)(blockIdx.y * BCHUNK) * sN + n;
    float*       op = out + (size_t)(blockIdx.y * BCHUNK) * sN + n;

    // Preload all 16 rows (8 v2f) -> 16 independent outstanding loads.
    // In-order vmcnt waits mean iter k blocks only on loads 4k..4k+3 while
    // the rest stay in flight (depth-3 software pipeline, zero extra instrs).
    v2f xr[8];
    #pragma unroll
    for (int r = 0; r < 8; ++r) {
        xr[r].x = sp[(size_t)(2*r)   * sN];
        xr[r].y = sp[(size_t)(2*r+1) * sN];
    }

    #pragma unroll
    for (int it = 0; it < 4; ++it) {
        v2f x[2], a0[2], a1[2], a2[2];
        x[0] = xr[2*it];
        x[1] = xr[2*it+1];

        #pragma unroll
        for (int c = 0; c < 2; ++c) {
            a0[c] = __builtin_elementwise_max(x[c], SPL(0.0f));
            a2[c] = __builtin_elementwise_min(x[c], SPL(0.0f));
            v2f u  = x[c] * x[c];
            v2f pn = fma2(fma2(fma2(cn3, u, cn2), u, cn1), u, vQ);
            v2f pd = fma2(fma2(fma2(cd3, u, cd2), u, cd1), u, vOne);
            a1[c]  = fma2(x[c] * pn, rcpv(pd), vH);
        }

        v2f h[2][4];
        #pragma unroll
        for (int c = 0; c < 2; ++c) {
            v2f qd[4], nm[4];
            #pragma unroll
            for (int j = 0; j < 4; ++j) {
                v2f zj = fma2(a0[c], w1[0][j],
                         fma2(a1[c], w1[1][j],
                         fma2(a2[c], w1[2][j],
                         fma2(x[c],  w1[3][j], bb1[j]))));
                v2f vv = zj * zj;
                v2f nn = fma2(fma2(fma2(cn3, vv, cn2), vv, cn1), vv, vQ);
                qd[j]  = fma2(fma2(fma2(cd3, vv, cd2), vv, cd1), vv, vOne);
                nm[j]  = zj * nn;
            }
            // one rcp for all 4 hidden sigmoids
            v2f p01 = qd[0] * qd[1];
            v2f p23 = qd[2] * qd[3];
            v2f rr  = rcpv(p01 * p23);
            v2f i01 = p23 * rr;              // 1/(qd0*qd1)
            v2f i23 = p01 * rr;              // 1/(qd2*qd3)
            h[c][0] = fma2(nm[0] * qd[1], i01, vH);
            h[c][1] = fma2(nm[1] * qd[0], i01, vH);
            h[c][2] = fma2(nm[2] * qd[3], i23, vH);
            h[c][3] = fma2(nm[3] * qd[2], i23, vH);
        }

        v2f o[2];
        #pragma unroll
        for (int c = 0; c < 2; ++c) {
            v2f l0 = fma2(h[c][0],w2[0][0], fma2(h[c][1],w2[1][0], fma2(h[c][2],w2[2][0], fma2(h[c][3],w2[3][0], bb2[0]))));
            v2f l1 = fma2(h[c][0],w2[0][1], fma2(h[c][1],w2[1][1], fma2(h[c][2],w2[2][1], fma2(h[c][3],w2[3][1], bb2[1]))));
            v2f l2 = fma2(h[c][0],w2[0][2], fma2(h[c][1],w2[1][2], fma2(h[c][2],w2[2][2], fma2(h[c][3],w2[3][2], bb2[2]))));
            v2f l3 = fma2(h[c][0],w2[0][3], fma2(h[c][1],w2[1][3], fma2(h[c][2],w2[2][3], fma2(h[c][3],w2[3][3], bb2[3]))));
            // softmax shifted by l3 (e3 == 1), log2 domain
            v2f e0 = exp2v(l0 - l3);
            v2f e1 = exp2v(l1 - l3);
            v2f e2 = exp2v(l2 - l3);
            v2f den = (e0 + e1) + (e2 + vOne);
            v2f num = fma2(e0, a0[c], fma2(e1, a1[c], fma2(e2, a2[c], x[c])));
            o[c] = num * rcpv(den);
        }

        op[(size_t)(4*it)   * sN] = o[0].x;
        op[(size_t)(4*it+1) * sN] = o[0].y;
        op[(size_t)(4*it+2) * sN] = o[1].x;
        op[(size_t)(4*it+3) * sN] = o[1].y;
    }
}

extern "C" void kernel_launch(void* const* d_in, const int* in_sizes, int n_in,
                              void* d_out, int out_size, void* d_ws, size_t ws_size,
                              hipStream_t stream) {
    const float* s  = (const float*)d_in[0];
    const float* W1 = (const float*)d_in[1];
    const float* b1 = (const float*)d_in[2];
    const float* W2 = (const float*)d_in[3];
    const float* b2 = (const float*)d_in[4];
    float* out = (float*)d_out;

    const int K = 4;
    const int N = in_sizes[2] / K;       // b1 is N*K
    const int B = in_sizes[0] / N;       // s is B*N

    dim3 grid(N / 256, B / 16);
    gatemix_kernel<<<grid, 256, 0, stream>>>(s, W1, b1, W2, b2, out, B, N);
}